// Round 11
// baseline (67.350 us; speedup 1.0000x reference)
//
#include <hip/hip_runtime.h>
#include <hip/hip_bf16.h>

// Problem constants
constexpr int BB = 8;
constexpr int LLEN = 2048;
constexpr int HH = 256;
constexpr int EE = 512;          // H * EXP
constexpr int MM = BB * LLEN;    // 16384 rows

typedef short bf16x8 __attribute__((ext_vector_type(8)));
typedef float f32x4  __attribute__((ext_vector_type(4)));

static __device__ inline unsigned short f2bf(float f) {
    unsigned u = __builtin_bit_cast(unsigned, f);
    unsigned r = (u + 0x7FFFu + ((u >> 16) & 1u)) >> 16;
    return (unsigned short)r;
}
static __device__ inline float bf2f(unsigned short h) {
    return __builtin_bit_cast(float, (unsigned)h << 16);
}

#define GL2LDS(gp, lp) __builtin_amdgcn_global_load_lds( \
    (const __attribute__((address_space(1))) void*)(gp), \
    (__attribute__((address_space(3))) void*)(lp), 16, 0, 0)

// ---------------------------------------------------------------------------
__global__ __launch_bounds__(256) void transpose_cast_kernel(
    const float* __restrict__ W, unsigned short* __restrict__ Wt, int K, int N)
{
    int i = blockIdx.x * 256 + threadIdx.x;
    if (i < K * N) {
        int n = i / K, k = i - n * K;
        Wt[i] = f2bf(W[(size_t)k * N + n]);
    }
}

// ---------------------------------------------------------------------------
// K1 rebuilt in KB's proven shape (R11): grid 256, 1 blk/CU, 512 threads.
// xz = u(f32, cast in-kernel) @ wtin^T + b_in; cols<512 -> x bf16,
// cols>=512 -> silu -> zs bf16 (row-major [MM][512] each).
// Per block: 64 rows. Stage A once (reg-cvt f32->bf16, swizzled ds_write);
// loop 8 chunks of 128 B-cols: gload_lds 64KB (source-XOR-swizzled, linear
// dest), vmcnt(0)+barrier, 8 K-steps MFMA, epilogue, barrier.
// LDS swizzle (both A and B): 16B slot s of row r at phys s^(r&7) ->
// reads spread 8 banks x 2-way (free).  LDS 96 KB.
// ---------------------------------------------------------------------------
__global__ __launch_bounds__(512) void k1_kb(
    const float* __restrict__ u, const unsigned short* __restrict__ Bt,
    const float* __restrict__ bias,
    unsigned short* __restrict__ xb, unsigned short* __restrict__ zsb)
{
    __shared__ unsigned short Abuf[64 * 256];    // 32 KB  [row][k]
    __shared__ unsigned short Bbuf[128 * 256];   // 64 KB  [colLocal][k]

    const int tid = threadIdx.x;
    const int lane = tid & 63;
    const int wave = tid >> 6;                   // 0..7
    const int wrow = wave >> 2, wcol = wave & 3; // 2 x 4 wave grid
    const int l15 = lane & 15;
    const int lk  = lane >> 4;

    const int b = blockIdx.x;
    const int lin = (b & 7) * 32 + (b >> 3);     // XCD-chunked (matches KB)
    const int r0 = lin * 64;

    // --- issue B chunk 0 DMA first (overlaps A cvt) ---
    #pragma unroll
    for (int i = 0; i < 8; ++i) {
        int sid = i * 512 + tid;                 // 0..4095
        int cc = sid >> 5, s = sid & 31;
        GL2LDS(Bt + (size_t)cc * 256 + ((s ^ (cc & 7)) << 3), &Bbuf[sid * 8]);
    }
    // --- stage A: 64 rows x 256 k, f32 -> bf16, swizzled ds_write ---
    #pragma unroll
    for (int i = 0; i < 8; ++i) {
        int idx = i * 512 + tid;                 // 0..4095
        int r = idx >> 6, c4 = idx & 63;         // row, float4-index
        f32x4 v = *reinterpret_cast<const f32x4*>(u + (size_t)(r0 + r) * 256 + (c4 << 2));
        ushort4 o = {f2bf(v[0]), f2bf(v[1]), f2bf(v[2]), f2bf(v[3])};
        int off = r * 256 + ((((c4 >> 1) ^ (r & 7)) << 3) | ((c4 & 1) << 2));
        *reinterpret_cast<ushort4*>(&Abuf[off]) = o;
    }

    for (int c = 0; c < 8; ++c) {
        if (c > 0) {
            #pragma unroll
            for (int i = 0; i < 8; ++i) {
                int sid = i * 512 + tid;
                int cc = sid >> 5, s = sid & 31;
                GL2LDS(Bt + (size_t)(c * 128 + cc) * 256 + ((s ^ (cc & 7)) << 3),
                       &Bbuf[sid * 8]);
            }
        }
        asm volatile("s_waitcnt vmcnt(0)" ::: "memory");
        __builtin_amdgcn_sched_barrier(0);
        __syncthreads();                         // chunk c (+A on c=0) ready

        f32x4 acc[2][2] = {};
        #pragma unroll
        for (int ks = 0; ks < 8; ++ks) {
            bf16x8 af[2], bf[2];
            #pragma unroll
            for (int m = 0; m < 2; ++m) {
                const int row = wrow * 32 + m * 16 + l15;
                af[m] = *reinterpret_cast<const bf16x8*>(
                    &Abuf[row * 256 + (((ks * 4 + lk) ^ (row & 7)) << 3)]);
            }
            #pragma unroll
            for (int n = 0; n < 2; ++n) {
                const int cl = wcol * 32 + n * 16 + l15;
                bf[n] = *reinterpret_cast<const bf16x8*>(
                    &Bbuf[cl * 256 + (((ks * 4 + lk) ^ (cl & 7)) << 3)]);
            }
            #pragma unroll
            for (int m = 0; m < 2; ++m)
                #pragma unroll
                for (int n = 0; n < 2; ++n)
                    acc[m][n] = __builtin_amdgcn_mfma_f32_16x16x32_bf16(
                        af[m], bf[n], acc[m][n], 0, 0, 0);
        }

        // epilogue: C/D layout col = lane&15, row = (lane>>4)*4 + i
        const bool zside = c >= 4;
        unsigned short* Cp = zside ? zsb : xb;
        #pragma unroll
        for (int m = 0; m < 2; ++m) {
            #pragma unroll
            for (int n = 0; n < 2; ++n) {
                const int gcol = c * 128 + wcol * 32 + n * 16 + l15;
                const float bv = bias[gcol];
                const int ocol = gcol - (zside ? 512 : 0);
                #pragma unroll
                for (int i = 0; i < 4; ++i) {
                    const int row = r0 + wrow * 32 + m * 16 + lk * 4 + i;
                    float v = acc[m][n][i] + bv;
                    if (zside) v = v / (1.f + __expf(-v));
                    Cp[(size_t)row * EE + ocol] = f2bf(v);
                }
            }
        }
        __syncthreads();                         // Bbuf free for next stage
    }
}

// ---------------------------------------------------------------------------
// KB: fused mid + GEMM3 (validated R6-R10, ~7us).  Block = 64 rows.
// Phase 1: conv(k=3)+SiLU+Dp+LN+*silu(z) -> g in LDS (bf16, swizzled write).
//          (SSM scan is constant over E -> cancelled by LN; W_x/b_x/A_log dead.)
// Phase 2: out = g @ W_out^T + b_out, K=512 single-shot per 64-col B-chunk;
//          B reg-staged coalesced + swizzled ds_write (T14 early loads).
// ---------------------------------------------------------------------------
__global__ __launch_bounds__(256, 1) void kb_mid_gemm3(
    const unsigned short* __restrict__ xb, const unsigned short* __restrict__ zsb,
    const unsigned short* __restrict__ Bt,   // wtout [256][512]
    const float* __restrict__ bias, float* __restrict__ out,
    const float* __restrict__ conv_w, const float* __restrict__ conv_b,
    const float* __restrict__ Dp, const float* __restrict__ ln_g,
    const float* __restrict__ ln_b)
{
    __shared__ unsigned short G[64 * 512];    // 64 KB
    __shared__ unsigned short Bl[64 * 512];   // 64 KB

    const int tid = threadIdx.x;
    const int lane = tid & 63;
    const int wave = tid >> 6;
    const int l15 = lane & 15;
    const int lk  = lane >> 4;

    const int b = blockIdx.x;
    const int lin = (b & 7) * 32 + (b >> 3);
    const int r0 = lin * 64;

    const int e0 = lane * 8;
    float cw0[8], cw1[8], cw2[8], cb8[8], dp8[8], lg8[8], lb8[8];
    #pragma unroll
    for (int j = 0; j < 8; ++j) {
        int e = e0 + j;
        cw0[j] = conv_w[e * 3 + 0];
        cw1[j] = conv_w[e * 3 + 1];
        cw2[j] = conv_w[e * 3 + 2];
        cb8[j] = conv_b[e];
        dp8[j] = Dp[e];
        lg8[j] = ln_g[e];
        lb8[j] = ln_b[e];
    }

    for (int it = 0; it < 16; ++it) {
        const int i = wave * 16 + it;
        const int gr = r0 + i;
        const int l = gr & (LLEN - 1);
        const size_t base = (size_t)gr * EE + e0;

        bf16x8 xc = *reinterpret_cast<const bf16x8*>(xb + base);
        bf16x8 xm = {}, xp = {};
        if (l > 0)        xm = *reinterpret_cast<const bf16x8*>(xb + base - EE);
        if (l < LLEN - 1) xp = *reinterpret_cast<const bf16x8*>(xb + base + EE);
        bf16x8 zv = *reinterpret_cast<const bf16x8*>(zsb + base);

        float o[8];
        float s1 = 0.f, s2 = 0.f;
        #pragma unroll
        for (int j = 0; j < 8; ++j) {
            float v = cb8[j]
                    + bf2f((unsigned short)xm[j]) * cw0[j]
                    + bf2f((unsigned short)xc[j]) * cw1[j]
                    + bf2f((unsigned short)xp[j]) * cw2[j];
            float sx = v / (1.f + __expf(-v));
            float oe = dp8[j] * sx;
            o[j] = oe;
            s1 += oe;
            s2 += oe * oe;
        }
        #pragma unroll
        for (int off = 1; off < 64; off <<= 1) {
            s1 += __shfl_xor(s1, off);
            s2 += __shfl_xor(s2, off);
        }
        const float mu  = s1 * (1.f / EE);
        const float var = s2 * (1.f / EE) - mu * mu;
        const float inv = rsqrtf(var + 1e-5f);

        bf16x8 gv;
        #pragma unroll
        for (int j = 0; j < 8; ++j) {
            float gy = ((o[j] - mu) * inv * lg8[j] + lb8[j]) * bf2f((unsigned short)zv[j]);
            gv[j] = (short)f2bf(gy);
        }
        *reinterpret_cast<bf16x8*>(&G[i * 512 + ((lane ^ (i & 7)) << 3)]) = gv;
    }

    // --- stage B chunk 0: coalesced global->reg, swizzled ds_write ---
    bf16x8 breg[16];
    #pragma unroll
    for (int i = 0; i < 16; ++i) {
        int id = i * 256 + tid;
        breg[i] = *reinterpret_cast<const bf16x8*>(Bt + (size_t)id * 8);
    }
    __syncthreads();                     // G complete (all waves)
    #pragma unroll
    for (int i = 0; i < 16; ++i) {
        int id = i * 256 + tid;
        int r = id >> 6, s = id & 63;
        *reinterpret_cast<bf16x8*>(&Bl[r * 512 + ((s ^ (r & 7)) << 3)]) = breg[i];
    }
    __syncthreads();                     // Bl chunk0 ready

    const int wrow = wave >> 1, wcol = wave & 1;
    for (int c = 0; c < 4; ++c) {
        if (c < 3) {                     // T14: issue next-chunk loads early
            #pragma unroll
            for (int i = 0; i < 16; ++i) {
                int id = (c + 1) * 4096 + i * 256 + tid;
                breg[i] = *reinterpret_cast<const bf16x8*>(Bt + (size_t)id * 8);
            }
        }
        f32x4 acc[2][2] = {};
        #pragma unroll
        for (int ks = 0; ks < 16; ++ks) {
            bf16x8 af[2], bfr[2];
            #pragma unroll
            for (int m = 0; m < 2; ++m) {
                const int ra = wrow * 32 + m * 16 + l15;
                const int ph = (ks * 4 + lk) ^ (ra & 7);
                af[m] = *reinterpret_cast<const bf16x8*>(&G[ra * 512 + ph * 8]);
            }
            #pragma unroll
            for (int n = 0; n < 2; ++n) {
                const int rb = wcol * 32 + n * 16 + l15;
                const int ph = (ks * 4 + lk) ^ (rb & 7);
                bfr[n] = *reinterpret_cast<const bf16x8*>(&Bl[rb * 512 + ph * 8]);
            }
            #pragma unroll
            for (int m = 0; m < 2; ++m)
                #pragma unroll
                for (int n = 0; n < 2; ++n)
                    acc[m][n] = __builtin_amdgcn_mfma_f32_16x16x32_bf16(
                        af[m], bfr[n], acc[m][n], 0, 0, 0);
        }
        #pragma unroll
        for (int m = 0; m < 2; ++m) {
            #pragma unroll
            for (int n = 0; n < 2; ++n) {
                int col = c * 64 + wcol * 32 + n * 16 + l15;
                float bv = bias[col];
                #pragma unroll
                for (int i = 0; i < 4; ++i) {
                    int row = r0 + wrow * 32 + m * 16 + lk * 4 + i;
                    out[(size_t)row * HH + col] = acc[m][n][i] + bv;
                }
            }
        }
        if (c < 3) {
            __syncthreads();
            #pragma unroll
            for (int i = 0; i < 16; ++i) {
                int id = i * 256 + tid;
                int r = id >> 6, s = id & 63;
                *reinterpret_cast<bf16x8*>(&Bl[r * 512 + ((s ^ (r & 7)) << 3)]) = breg[i];
            }
            __syncthreads();
        }
    }
}

// ---------------------------------------------------------------------------
extern "C" void kernel_launch(void* const* d_in, const int* in_sizes, int n_in,
                              void* d_out, int out_size, void* d_ws, size_t ws_size,
                              hipStream_t stream)
{
    const float* u      = (const float*)d_in[0];
    const float* W_in   = (const float*)d_in[1];
    const float* b_in   = (const float*)d_in[2];
    const float* conv_w = (const float*)d_in[3];
    const float* conv_b = (const float*)d_in[4];
    // d_in[5]=W_x, d_in[6]=b_x, d_in[7]=A_log: dead (scan cancels under LN)
    const float* Dp     = (const float*)d_in[8];
    const float* W_out  = (const float*)d_in[9];
    const float* b_out  = (const float*)d_in[10];
    const float* ln_g   = (const float*)d_in[11];
    const float* ln_b   = (const float*)d_in[12];
    float* out = (float*)d_out;

    char* ws = (char*)d_ws;
    unsigned short* wtin  = (unsigned short*)ws; ws += (size_t)1024 * HH * 2;  // [1024][256]
    unsigned short* wtout = (unsigned short*)ws; ws += (size_t)HH * EE * 2;    // [256][512]
    unsigned short* xbuf  = (unsigned short*)ws; ws += (size_t)MM * EE * 2;
    unsigned short* zsbuf = (unsigned short*)ws;

    dim3 blk(256);

    transpose_cast_kernel<<<dim3((1024 * HH + 255) / 256), blk, 0, stream>>>(W_in, wtin, HH, 1024);
    transpose_cast_kernel<<<dim3((HH * EE + 255) / 256), blk, 0, stream>>>(W_out, wtout, EE, HH);

    // K1 in KB shape: grid 256, 512 threads, 1 blk/CU
    k1_kb<<<dim3(256), dim3(512), 0, stream>>>(u, wtin, b_in, xbuf, zsbuf);

    // KB: fused mid+GEMM3
    kb_mid_gemm3<<<dim3(256), blk, 0, stream>>>(
        xbuf, zsbuf, wtout, b_out, out, conv_w, conv_b, Dp, ln_g, ln_b);
}

// Round 12
// 63.045 us; speedup vs baseline: 1.0683x; 1.0683x over previous
//
#include <hip/hip_runtime.h>
#include <hip/hip_bf16.h>

// Problem constants
constexpr int BB = 8;
constexpr int LLEN = 2048;
constexpr int HH = 256;
constexpr int EE = 512;          // H * EXP
constexpr int MM = BB * LLEN;    // 16384 rows

typedef short bf16x8 __attribute__((ext_vector_type(8)));
typedef float f32x4  __attribute__((ext_vector_type(4)));

static __device__ inline unsigned short f2bf(float f) {
    unsigned u = __builtin_bit_cast(unsigned, f);
    unsigned r = (u + 0x7FFFu + ((u >> 16) & 1u)) >> 16;
    return (unsigned short)r;
}
static __device__ inline float bf2f(unsigned short h) {
    return __builtin_bit_cast(float, (unsigned)h << 16);
}

#define GL2LDS(gp, lp) __builtin_amdgcn_global_load_lds( \
    (const __attribute__((address_space(1))) void*)(gp), \
    (__attribute__((address_space(3))) void*)(lp), 16, 0, 0)

// ---------------------------------------------------------------------------
// prep: both weight transposes in ONE kernel.
// wtin[n][k]  = bf16(W_in[k][n])   n<1024, k<256
// wtout[n][k] = bf16(W_out[k][n])  n<256,  k<512
// ---------------------------------------------------------------------------
__global__ __launch_bounds__(256) void prep_weights(
    const float* __restrict__ W_in, const float* __restrict__ W_out,
    unsigned short* __restrict__ wtin, unsigned short* __restrict__ wtout)
{
    int i = blockIdx.x * 256 + threadIdx.x;
    if (i < 1024 * 256) {
        int n = i >> 8, k = i & 255;
        wtin[i] = f2bf(W_in[(size_t)k * 1024 + n]);
    } else {
        int j = i - 1024 * 256;
        if (j < 256 * 512) {
            int n = j >> 9, k = j & 511;
            wtout[j] = f2bf(W_out[(size_t)k * 256 + n]);
        }
    }
}

// ---------------------------------------------------------------------------
// MEGA: GEMM1 + conv/SiLU/Dp/LN/silu(z) + GEMM3 fused, one block = 64 rows.
// - SSM scan output is constant over E (h0=0, input term broadcasts over E),
//   so LayerNorm cancels it exactly -> skipped; W_x/b_x/A_log dead.
// - Conv halo (rows r0-1, r0+64) computed IN-BLOCK by an overlapping-MFMA
//   trick: x-pass covers 66 rows with m-frag starts {0,16,32,48,50}
//   (rows 50..63 double-computed, identical values -> benign).
// - LDS plan (133120 B, 1 blk/CU, 512 thr):
//     region0 [0,67584):  A[66][256] (0..33792) + Bchunk[64][256] (33792..66560)
//                         -> later overlaid by XT x-tile [66][512]
//                         -> later overlaid by WB wtout-chunk [64][512]
//     ZS [67584,133120):  zs[64][512], overwritten in place by g, then = GEMM3 A
// - All LDS tiles XOR-swizzled: 16B slot s of row r at phys s^(r&7)
//   (gload_lds: pre-swizzled global source + linear dest; ds_write: direct).
// ---------------------------------------------------------------------------
__global__ __launch_bounds__(512, 1) void mega(
    const float* __restrict__ u,
    const unsigned short* __restrict__ wtin,   // [1024][256]
    const unsigned short* __restrict__ wtout,  // [256][512]
    const float* __restrict__ b_in, const float* __restrict__ b_out,
    const float* __restrict__ conv_w, const float* __restrict__ conv_b,
    const float* __restrict__ Dp, const float* __restrict__ ln_g,
    const float* __restrict__ ln_b, float* __restrict__ out)
{
    __shared__ __align__(16) char LDSB[133120];
    unsigned short* A  = (unsigned short*)LDSB;             // [66][256]
    unsigned short* Bs = (unsigned short*)(LDSB + 33792);   // [64][256]
    unsigned short* XT = (unsigned short*)LDSB;             // [66][512] overlay
    unsigned short* WB = (unsigned short*)LDSB;             // [64][512] overlay
    unsigned short* ZS = (unsigned short*)(LDSB + 67584);   // [64][512]

    const int tid = threadIdx.x;
    const int lane = tid & 63;
    const int wave = tid >> 6;                // 0..7
    const int l15 = lane & 15;
    const int lk  = lane >> 4;
    const int g  = wave >> 2;                 // m-group
    const int nf = wave & 3;                  // n-frag (16-col strip)

    const int b = blockIdx.x;
    const int lin = (b & 7) * 32 + (b >> 3);  // XCD-chunked
    const int r0 = lin * 64;

    // ---- stage wtin chunk 0 (async DMA) ----
    auto stageB = [&](int t) {
        const unsigned short* src = wtin + (size_t)t * 64 * 256;
        #pragma unroll
        for (int i = 0; i < 4; ++i) {
            int sid = i * 512 + tid;          // 0..2047
            int cc = sid >> 5, s = sid & 31;
            GL2LDS(src + cc * 256 + ((s ^ (cc & 7)) << 3), &Bs[sid * 8]);
        }
    };
    stageB(0);

    // ---- stage A: 66 rows (r0-1 .. r0+64, clamped), f32->bf16, swizzled ----
    #pragma unroll
    for (int i = 0; i < 9; ++i) {
        int idx = i * 512 + tid;
        if (idx < 66 * 64) {
            int rl = idx >> 6, c4 = idx & 63;
            int gr = r0 - 1 + rl;
            gr = gr < 0 ? 0 : (gr >= MM ? MM - 1 : gr);
            f32x4 v = *reinterpret_cast<const f32x4*>(u + (size_t)gr * 256 + (c4 << 2));
            ushort4 o = {f2bf(v[0]), f2bf(v[1]), f2bf(v[2]), f2bf(v[3])};
            int off = rl * 256 + ((((c4 >> 1) ^ (rl & 7)) << 3) | ((c4 & 1) << 2));
            *reinterpret_cast<ushort4*>(&A[off]) = o;
        }
    }

    // ---- 16 chunks of 64 wtin-cols: t<8 -> x (acc held), t>=8 -> z ----
    f32x4 accX[3][8] = {};
    #pragma unroll
    for (int t = 0; t < 16; ++t) {
        __syncthreads();   // chunk t staged (drains vmcnt+lgkm) & prior reads done

        const int cb = nf * 16 + l15;
        if (t < 8) {
            #pragma unroll
            for (int ks = 0; ks < 8; ++ks) {
                bf16x8 bv = *reinterpret_cast<const bf16x8*>(
                    &Bs[cb * 256 + (((ks * 4 + lk) ^ (cb & 7)) << 3)]);
                #pragma unroll
                for (int m = 0; m < 3; ++m) {
                    if (g == 0 || m < 2) {
                        const int S = g ? (m == 0 ? 48 : 50) : m * 16;
                        const int ra = S + l15;
                        bf16x8 av = *reinterpret_cast<const bf16x8*>(
                            &A[ra * 256 + (((ks * 4 + lk) ^ (ra & 7)) << 3)]);
                        accX[m][t] = __builtin_amdgcn_mfma_f32_16x16x32_bf16(
                            av, bv, accX[m][t], 0, 0, 0);
                    }
                }
            }
        } else {
            f32x4 az[2] = {};
            #pragma unroll
            for (int ks = 0; ks < 8; ++ks) {
                bf16x8 bv = *reinterpret_cast<const bf16x8*>(
                    &Bs[cb * 256 + (((ks * 4 + lk) ^ (cb & 7)) << 3)]);
                #pragma unroll
                for (int m = 0; m < 2; ++m) {
                    const int S = (g ? 33 : 1) + m * 16;
                    const int ra = S + l15;
                    bf16x8 av = *reinterpret_cast<const bf16x8*>(
                        &A[ra * 256 + (((ks * 4 + lk) ^ (ra & 7)) << 3)]);
                    az[m] = __builtin_amdgcn_mfma_f32_16x16x32_bf16(
                        av, bv, az[m], 0, 0, 0);
                }
            }
            // z epilogue: +bias, silu, -> ZS (zs row = A-row - 1)
            #pragma unroll
            for (int m = 0; m < 2; ++m) {
                const int S = (g ? 33 : 1) + m * 16;
                const int col = (t - 8) * 64 + nf * 16 + l15;
                const float bv = b_in[512 + col];
                #pragma unroll
                for (int i = 0; i < 4; ++i) {
                    int zr = S + lk * 4 + i - 1;
                    float v = az[m][i] + bv;
                    v = v / (1.f + __expf(-v));
                    ZS[zr * 512 + ((((col >> 3) ^ (zr & 7)) << 3) | (col & 7))] = f2bf(v);
                }
            }
        }
        __syncthreads();   // all reads of Bs chunk t done
        if (t < 15) stageB(t + 1);
    }

    // ---- x epilogue: accX (+bias) -> XT (overlays A+Bs, now dead) ----
    #pragma unroll
    for (int m = 0; m < 3; ++m) {
        if (g == 0 || m < 2) {
            const int S = g ? (m == 0 ? 48 : 50) : m * 16;
            #pragma unroll
            for (int t = 0; t < 8; ++t) {
                const int col = t * 64 + nf * 16 + l15;
                const float bv = b_in[col];
                #pragma unroll
                for (int i = 0; i < 4; ++i) {
                    int row = S + lk * 4 + i;
                    XT[row * 512 + ((((col >> 3) ^ (row & 7)) << 3) | (col & 7))] =
                        f2bf(accX[m][t][i] + bv);
                }
            }
        }
    }
    __syncthreads();

    // ---- mid: conv+SiLU+Dp+LN+*silu(z); g overwrites ZS in place ----
    const int e0 = lane * 8;
    float cw0[8], cw1[8], cw2[8], cb8[8], dp8[8], lg8[8], lb8[8];
    #pragma unroll
    for (int j = 0; j < 8; ++j) {
        int e = e0 + j;
        cw0[j] = conv_w[e * 3 + 0];
        cw1[j] = conv_w[e * 3 + 1];
        cw2[j] = conv_w[e * 3 + 2];
        cb8[j] = conv_b[e];
        dp8[j] = Dp[e];
        lg8[j] = ln_g[e];
        lb8[j] = ln_b[e];
    }
    for (int it = 0; it < 8; ++it) {
        const int i = wave * 8 + it;             // local out-row 0..63
        const int l = (r0 + i) & (LLEN - 1);
        auto rdXT = [&](int rl) {
            return *reinterpret_cast<const bf16x8*>(
                &XT[rl * 512 + (((e0 >> 3) ^ (rl & 7)) << 3)]);
        };
        bf16x8 xc = rdXT(i + 1);
        bf16x8 xm = {}, xp = {};
        if (l > 0)        xm = rdXT(i);
        if (l < LLEN - 1) xp = rdXT(i + 2);
        const int zoff = i * 512 + (((e0 >> 3) ^ (i & 7)) << 3);
        bf16x8 zv = *reinterpret_cast<const bf16x8*>(&ZS[zoff]);

        float o[8];
        float s1 = 0.f, s2 = 0.f;
        #pragma unroll
        for (int j = 0; j < 8; ++j) {
            float v = cb8[j]
                    + bf2f((unsigned short)xm[j]) * cw0[j]
                    + bf2f((unsigned short)xc[j]) * cw1[j]
                    + bf2f((unsigned short)xp[j]) * cw2[j];
            float sx = v / (1.f + __expf(-v));
            float oe = dp8[j] * sx;
            o[j] = oe;
            s1 += oe;
            s2 += oe * oe;
        }
        #pragma unroll
        for (int off = 1; off < 64; off <<= 1) {
            s1 += __shfl_xor(s1, off);
            s2 += __shfl_xor(s2, off);
        }
        const float mu  = s1 * (1.f / EE);
        const float var = s2 * (1.f / EE) - mu * mu;
        const float inv = rsqrtf(var + 1e-5f);

        bf16x8 gv;
        #pragma unroll
        for (int j = 0; j < 8; ++j) {
            float gy = ((o[j] - mu) * inv * lg8[j] + lb8[j]) * bf2f((unsigned short)zv[j]);
            gv[j] = (short)f2bf(gy);
        }
        *reinterpret_cast<bf16x8*>(&ZS[zoff]) = gv;   // g in place
    }
    __syncthreads();   // XT dead; ZS = g complete

    // ---- GEMM3: out = g @ wtout^T + b_out; 4 chunks of 64 out-cols ----
    auto stageW = [&](int c) {
        const unsigned short* src = wtout + (size_t)c * 64 * 512;
        #pragma unroll
        for (int i = 0; i < 8; ++i) {
            int sid = i * 512 + tid;          // 0..4095
            int cc = sid >> 6, s = sid & 63;
            GL2LDS(src + cc * 512 + ((s ^ (cc & 7)) << 3), &WB[sid * 8]);
        }
    };
    stageW(0);
    const int mh = g;                          // 2 m-frags per wave
    for (int c = 0; c < 4; ++c) {
        __syncthreads();                       // WB chunk staged
        f32x4 ac[2] = {};
        #pragma unroll
        for (int ks = 0; ks < 16; ++ks) {
            const int cb = nf * 16 + l15;
            bf16x8 bv = *reinterpret_cast<const bf16x8*>(
                &WB[cb * 512 + (((ks * 4 + lk) ^ (cb & 7)) << 3)]);
            #pragma unroll
            for (int m = 0; m < 2; ++m) {
                const int ra = (mh * 2 + m) * 16 + l15;
                bf16x8 av = *reinterpret_cast<const bf16x8*>(
                    &ZS[ra * 512 + (((ks * 4 + lk) ^ (ra & 7)) << 3)]);
                ac[m] = __builtin_amdgcn_mfma_f32_16x16x32_bf16(av, bv, ac[m], 0, 0, 0);
            }
        }
        #pragma unroll
        for (int m = 0; m < 2; ++m) {
            const int col = c * 64 + nf * 16 + l15;
            const float bv = b_out[col];
            #pragma unroll
            for (int i = 0; i < 4; ++i) {
                int row = r0 + (mh * 2 + m) * 16 + lk * 4 + i;
                out[(size_t)row * HH + col] = ac[m][i] + bv;
            }
        }
        __syncthreads();                       // WB reads done
        if (c < 3) stageW(c + 1);
    }
}

// ---------------------------------------------------------------------------
extern "C" void kernel_launch(void* const* d_in, const int* in_sizes, int n_in,
                              void* d_out, int out_size, void* d_ws, size_t ws_size,
                              hipStream_t stream)
{
    const float* u      = (const float*)d_in[0];
    const float* W_in   = (const float*)d_in[1];
    const float* b_in   = (const float*)d_in[2];
    const float* conv_w = (const float*)d_in[3];
    const float* conv_b = (const float*)d_in[4];
    // d_in[5]=W_x, d_in[6]=b_x, d_in[7]=A_log: dead (scan cancels under LN)
    const float* Dp     = (const float*)d_in[8];
    const float* W_out  = (const float*)d_in[9];
    const float* b_out  = (const float*)d_in[10];
    const float* ln_g   = (const float*)d_in[11];
    const float* ln_b   = (const float*)d_in[12];
    float* out = (float*)d_out;

    char* ws = (char*)d_ws;
    unsigned short* wtin  = (unsigned short*)ws; ws += (size_t)1024 * HH * 2;  // [1024][256]
    unsigned short* wtout = (unsigned short*)ws;                               // [256][512]

    // prep: merged weight transposes
    prep_weights<<<dim3(1536), dim3(256), 0, stream>>>(W_in, W_out, wtin, wtout);

    // mega: GEMM1 + mid + GEMM3, grid 256 (1 blk/CU), 512 threads
    mega<<<dim3(256), dim3(512), 0, stream>>>(
        u, wtin, wtout, b_in, b_out, conv_w, conv_b, Dp, ln_g, ln_b, out);
}